// Round 4
// baseline (26.550 us; speedup 1.0000x reference)
//
#include <hip/hip_runtime.h>
#include <math.h>

#define NBATCH 8
#define PTOT   4096
#define NG     2048              // points per group
#define S      16                // ref slices per problem
#define SLEN   (NG / S)          // 128 refs per slice
#define QPT    8                 // queries per thread (consecutive)
#define NT     256               // threads per block
#define NPROB  32                // 8 batches x 2 groups x 2 directions
#define NBLK1  (NPROB * S)       // 512 blocks, pass 1
#define NPART  (NPROB * S * NG)  // per-slice per-query partial mins (1M floats)

// d_ws layout: [0..7] u64 fixed-point accumulator, [8..11] u32 arrival counter,
//              [64..] pmin (1M floats). Pass1 block 0 zeroes acc/cnt each call.

// Pass 1: one block = (problem, ref-slice). Each thread owns 8 CONSECUTIVE
// queries (96B contiguous -> 6 float4 loads, hoisted above the barrier).
// Ref slice staged via 96 float4 global loads -> LDS raw -> AoS (x,y,z,|r|^2).
// Inner: per ref point one broadcast ds_read_b128 feeds 8 dot products;
// min merged via fminf(fminf(t0,t1),mn) -> v_min3_f32.
__global__ __launch_bounds__(256) void chamfer_pass1(
    const float* __restrict__ x, const float* __restrict__ y,
    float* __restrict__ pmin,
    unsigned long long* __restrict__ acc, unsigned* __restrict__ cnt)
{
    __shared__ float  raw[SLEN * 3];   // 1.5 KiB
    __shared__ float4 ref[SLEN];       // 2 KiB

    const int blk   = blockIdx.x;
    const int tid   = threadIdx.x;

    // Zero the cross-kernel accumulator once per launch (pass2 runs strictly
    // after this kernel on the same stream, so visibility is guaranteed).
    if (blk == 0 && tid == 0) { *acc = 0ULL; *cnt = 0u; }

    const int slice = blk & (S - 1);
    const int prob  = blk >> 4;              // 0..31
    const int dir   = prob >> 4;             // 0: x->y, 1: y->x
    const int bg    = prob & 15;
    const int b     = bg >> 1;               // batch
    const int g     = bg & 1;                // group

    const float* qb = (dir == 0 ? x : y) + (size_t)(b * PTOT + g * NG) * 3;
    const float* rb = (dir == 0 ? y : x) + (size_t)(b * PTOT + g * NG) * 3;

    // Stage ref slice: 384 floats = 96 float4 (16B-aligned).
    if (tid < (SLEN * 3) / 4) {
        float4 v = ((const float4*)(rb + slice * SLEN * 3))[tid];
        ((float4*)raw)[tid] = v;
    }

    // Query loads (independent of staging -> overlap latency with barrier).
    float4 qv[6];
    {
        const float4* qp = (const float4*)(qb + (size_t)tid * QPT * 3);
        #pragma unroll
        for (int i = 0; i < 6; i++) qv[i] = qp[i];
    }

    __syncthreads();

    // Build AoS ref (x,y,z,|r|^2) from raw.
    if (tid < SLEN) {
        float rx = raw[tid * 3 + 0];
        float ry = raw[tid * 3 + 1];
        float rz = raw[tid * 3 + 2];
        ref[tid] = make_float4(rx, ry, rz, fmaf(rx, rx, fmaf(ry, ry, rz * rz)));
    }

    // Unpack queries while LDS settles.
    float ax[QPT], ay[QPT], az[QPT], qn[QPT], mn[QPT];
    const float* qf = reinterpret_cast<const float*>(qv);
    #pragma unroll
    for (int k = 0; k < QPT; k++) {
        float qx = qf[k * 3 + 0];
        float qy = qf[k * 3 + 1];
        float qz = qf[k * 3 + 2];
        ax[k] = -2.0f * qx; ay[k] = -2.0f * qy; az[k] = -2.0f * qz;
        qn[k] = fmaf(qx, qx, fmaf(qy, qy, qz * qz));
        mn[k] = 3.4e38f;
    }

    __syncthreads();

    // 8 independent chains; per 4 refs x 8 queries: 96 FMA + 16 min3.
    #pragma unroll 2
    for (int n = 0; n < SLEN; n += 4) {
        float4 r0 = ref[n + 0];
        float4 r1 = ref[n + 1];
        float4 r2 = ref[n + 2];
        float4 r3 = ref[n + 3];
        #pragma unroll
        for (int k = 0; k < QPT; k++) {
            float t0 = fmaf(r0.z, az[k], fmaf(r0.y, ay[k], fmaf(r0.x, ax[k], r0.w)));
            float t1 = fmaf(r1.z, az[k], fmaf(r1.y, ay[k], fmaf(r1.x, ax[k], r1.w)));
            float t2 = fmaf(r2.z, az[k], fmaf(r2.y, ay[k], fmaf(r2.x, ax[k], r2.w)));
            float t3 = fmaf(r3.z, az[k], fmaf(r3.y, ay[k], fmaf(r3.x, ax[k], r3.w)));
            mn[k] = fminf(fminf(t0, t1), mn[k]);   // -> v_min3_f32
            mn[k] = fminf(fminf(t2, t3), mn[k]);   // -> v_min3_f32
        }
    }

    // 8 contiguous floats per thread -> 2x global_store_dwordx4.
    float* op = pmin + (size_t)(prob * S + slice) * NG + tid * QPT;
    #pragma unroll
    for (int k = 0; k < QPT; k++)
        op[k] = mn[k] + qn[k];
}

// Pass 2 (fused with finalize): per (problem, query) min over 16 slices,
// sqrt, block-sum, fixed-point (2^32) u64 atomicAdd; last-arriving block
// converts and writes out[0]. Integer adds are associative -> deterministic.
__global__ __launch_bounds__(256) void chamfer_pass2(
    const float* __restrict__ pmin,
    unsigned long long* __restrict__ acc, unsigned* __restrict__ cnt,
    float* __restrict__ out)
{
    __shared__ float s4[4];
    const int tid  = threadIdx.x;
    const int gid  = blockIdx.x * 256 + tid;           // 0..65535
    const int prob = gid >> 11;                        // /2048
    const int q    = gid & (NG - 1);

    float m = 3.4e38f;
    #pragma unroll
    for (int s = 0; s < S; s++)
        m = fminf(m, pmin[(size_t)(prob * S + s) * NG + q]);

    float d = sqrtf(fmaxf(m, 0.0f));   // guard cancellation

    for (int off = 32; off > 0; off >>= 1)
        d += __shfl_down(d, off, 64);
    if ((tid & 63) == 0) s4[tid >> 6] = d;
    __syncthreads();

    if (tid == 0) {
        float bs = (s4[0] + s4[1]) + (s4[2] + s4[3]);      // block partial (<= ~2^12)
        // Exact power-of-two scaling of a f32 -> u64 conversion is exact.
        unsigned long long v = (unsigned long long)(bs * 4294967296.0f);
        atomicAdd(acc, v);
        __threadfence();
        unsigned old = atomicAdd(cnt, 1u);
        if (old == 255u) {                                 // last block
            __threadfence();
            unsigned long long total = atomicAdd(acc, 0ULL);
            out[0] = (float)((double)total * (1.0 / 4294967296.0) / 16384.0);
        }
    }
}

extern "C" void kernel_launch(void* const* d_in, const int* in_sizes, int n_in,
                              void* d_out, int out_size, void* d_ws, size_t ws_size,
                              hipStream_t stream) {
    const float* x = (const float*)d_in[0];
    const float* y = (const float*)d_in[1];
    float* out = (float*)d_out;

    unsigned long long* acc = (unsigned long long*)d_ws;
    unsigned*           cnt = (unsigned*)((char*)d_ws + 8);
    float*              pmin = (float*)((char*)d_ws + 64);   // 1M floats (4 MB)

    chamfer_pass1<<<NBLK1, NT, 0, stream>>>(x, y, pmin, acc, cnt);
    chamfer_pass2<<<256, NT, 0, stream>>>(pmin, acc, cnt, out);
}

// Round 5
// 21.828 us; speedup vs baseline: 1.2163x; 1.2163x over previous
//
#include <hip/hip_runtime.h>
#include <math.h>

typedef float v2f __attribute__((ext_vector_type(2)));

#if __has_builtin(__builtin_elementwise_fma)
#define FMA2(a, b, c) __builtin_elementwise_fma((a), (b), (c))
#else
static __device__ __forceinline__ v2f FMA2(v2f a, v2f b, v2f c) {
    v2f r; r.x = fmaf(a.x, b.x, c.x); r.y = fmaf(a.y, b.y, c.y); return r;
}
#endif

#define NBATCH 8
#define PTOT   4096
#define NG     2048              // points per group
#define S      16                // ref slices per problem
#define SLEN   (NG / S)          // 128 refs per slice
#define QPT    8                 // queries per thread (consecutive)
#define NT     256               // threads per block
#define NPROB  32                // 8 batches x 2 groups x 2 directions
#define NBLK1  (NPROB * S)       // 512 blocks, pass 1
#define NPART  (NPROB * S * NG)  // per-slice per-query partial mins (1M floats)

// Pass 1: one block = (problem, ref-slice). Each thread owns 8 consecutive
// queries. Refs staged to LDS in SoA-of-float4 (X,Y,Z,|r|^2 per 4 refs) so the
// inner loop runs PACKED fp32: per 4 refs x query = 6 v_pk_fma_f32 + 2 min3
// = 2.0 VALU instr per pair (vs 3.5 scalar).
__global__ __launch_bounds__(256) void chamfer_pass1(
    const float* __restrict__ x, const float* __restrict__ y,
    float* __restrict__ pmin)
{
    __shared__ float  raw[SLEN * 3];     // 1.5 KiB
    __shared__ float4 refX[SLEN / 4];    // x of refs 4i..4i+3
    __shared__ float4 refY[SLEN / 4];
    __shared__ float4 refZ[SLEN / 4];
    __shared__ float4 refW[SLEN / 4];    // |r|^2

    const int blk   = blockIdx.x;
    const int tid   = threadIdx.x;
    const int slice = blk & (S - 1);
    const int prob  = blk >> 4;              // 0..31
    const int dir   = prob >> 4;             // 0: x->y, 1: y->x
    const int bg    = prob & 15;
    const int b     = bg >> 1;               // batch
    const int g     = bg & 1;                // group

    const float* qb = (dir == 0 ? x : y) + (size_t)(b * PTOT + g * NG) * 3;
    const float* rb = (dir == 0 ? y : x) + (size_t)(b * PTOT + g * NG) * 3;

    // Stage ref slice: 384 floats = 96 float4 (16B-aligned).
    if (tid < (SLEN * 3) / 4) {
        float4 v = ((const float4*)(rb + slice * SLEN * 3))[tid];
        ((float4*)raw)[tid] = v;
    }

    // Query loads (independent of staging -> overlap latency with barrier).
    float4 qv[6];
    {
        const float4* qp = (const float4*)(qb + (size_t)tid * QPT * 3);
        #pragma unroll
        for (int i = 0; i < 6; i++) qv[i] = qp[i];
    }

    __syncthreads();

    // Transpose to SoA-of-float4 (32 threads, one 4-ref chunk each).
    if (tid < SLEN / 4) {
        const float* p = raw + tid * 12;
        float x0 = p[0], y0 = p[1],  z0 = p[2];
        float x1 = p[3], y1 = p[4],  z1 = p[5];
        float x2 = p[6], y2 = p[7],  z2 = p[8];
        float x3 = p[9], y3 = p[10], z3 = p[11];
        refX[tid] = make_float4(x0, x1, x2, x3);
        refY[tid] = make_float4(y0, y1, y2, y3);
        refZ[tid] = make_float4(z0, z1, z2, z3);
        refW[tid] = make_float4(fmaf(x0, x0, fmaf(y0, y0, z0 * z0)),
                                fmaf(x1, x1, fmaf(y1, y1, z1 * z1)),
                                fmaf(x2, x2, fmaf(y2, y2, z2 * z2)),
                                fmaf(x3, x3, fmaf(y3, y3, z3 * z3)));
    }

    // Unpack queries while LDS settles (duplicated halves for pk ops).
    v2f ax2[QPT], ay2[QPT], az2[QPT];
    float qn[QPT], mn[QPT];
    const float* qf = reinterpret_cast<const float*>(qv);
    #pragma unroll
    for (int k = 0; k < QPT; k++) {
        float qx = qf[k * 3 + 0];
        float qy = qf[k * 3 + 1];
        float qz = qf[k * 3 + 2];
        float ax = -2.0f * qx, ay = -2.0f * qy, az = -2.0f * qz;
        ax2[k] = (v2f){ax, ax};
        ay2[k] = (v2f){ay, ay};
        az2[k] = (v2f){az, az};
        qn[k] = fmaf(qx, qx, fmaf(qy, qy, qz * qz));
        mn[k] = 3.4e38f;
    }

    __syncthreads();

    // Inner loop: 4 refs/iter, packed 2-wide fp32. Per iter: 4 ds_read_b128
    // + 8 queries x (6 pk_fma + 2 min3) = 64 VALU instr (128 cyc) vs 48 cyc LDS.
    #pragma unroll 2
    for (int n4 = 0; n4 < SLEN / 4; n4++) {
        float4 X = refX[n4], Y = refY[n4], Z = refZ[n4], W = refW[n4];
        v2f X01 = (v2f){X.x, X.y}, X23 = (v2f){X.z, X.w};
        v2f Y01 = (v2f){Y.x, Y.y}, Y23 = (v2f){Y.z, Y.w};
        v2f Z01 = (v2f){Z.x, Z.y}, Z23 = (v2f){Z.z, Z.w};
        v2f W01 = (v2f){W.x, W.y}, W23 = (v2f){W.z, W.w};
        #pragma unroll
        for (int k = 0; k < QPT; k++) {
            v2f t01 = FMA2(X01, ax2[k], W01);
            t01     = FMA2(Y01, ay2[k], t01);
            t01     = FMA2(Z01, az2[k], t01);
            v2f t23 = FMA2(X23, ax2[k], W23);
            t23     = FMA2(Y23, ay2[k], t23);
            t23     = FMA2(Z23, az2[k], t23);
            mn[k] = fminf(fminf(t01.x, t01.y), mn[k]);   // -> v_min3_f32
            mn[k] = fminf(fminf(t23.x, t23.y), mn[k]);   // -> v_min3_f32
        }
    }

    // 8 contiguous floats per thread -> 2x global_store_dwordx4.
    float* op = pmin + (size_t)(prob * S + slice) * NG + tid * QPT;
    #pragma unroll
    for (int k = 0; k < QPT; k++)
        op[k] = mn[k] + qn[k];
}

// Pass 2: per (problem, query) min over the 16 slices, sqrt, block-sum.
__global__ __launch_bounds__(256) void chamfer_pass2(
    const float* __restrict__ pmin, float* __restrict__ bsum)
{
    __shared__ float s4[4];
    const int gid  = blockIdx.x * 256 + threadIdx.x;   // 0..65535
    const int prob = gid >> 11;                        // /2048
    const int q    = gid & (NG - 1);

    float m0 = 3.4e38f, m1 = 3.4e38f;
    #pragma unroll
    for (int s = 0; s < S; s += 2) {
        m0 = fminf(m0, pmin[(size_t)(prob * S + s) * NG + q]);
        m1 = fminf(m1, pmin[(size_t)(prob * S + s + 1) * NG + q]);
    }
    float m = fminf(m0, m1);

    float d = sqrtf(fmaxf(m, 0.0f));   // guard cancellation

    for (int off = 32; off > 0; off >>= 1)
        d += __shfl_down(d, off, 64);
    if ((threadIdx.x & 63) == 0) s4[threadIdx.x >> 6] = d;
    __syncthreads();
    if (threadIdx.x == 0)
        bsum[blockIdx.x] = (s4[0] + s4[1]) + (s4[2] + s4[3]);
}

// Pass 3: deterministic reduction of the 256 block sums.
__global__ __launch_bounds__(256) void chamfer_pass3(
    const float* __restrict__ bsum, float* __restrict__ out)
{
    __shared__ float s4[4];
    const int tid = threadIdx.x;
    float v = bsum[tid];
    for (int off = 32; off > 0; off >>= 1)
        v += __shfl_down(v, off, 64);
    if ((tid & 63) == 0) s4[tid >> 6] = v;
    __syncthreads();
    if (tid == 0)
        out[0] = ((s4[0] + s4[1]) + (s4[2] + s4[3])) * (1.0f / 16384.0f);
}

extern "C" void kernel_launch(void* const* d_in, const int* in_sizes, int n_in,
                              void* d_out, int out_size, void* d_ws, size_t ws_size,
                              hipStream_t stream) {
    const float* x = (const float*)d_in[0];
    const float* y = (const float*)d_in[1];
    float* out  = (float*)d_out;
    float* pmin = (float*)d_ws;                 // 1M floats (4 MB)
    float* bsum = pmin + NPART;                 // 256 floats

    chamfer_pass1<<<NBLK1, NT, 0, stream>>>(x, y, pmin);
    chamfer_pass2<<<256, NT, 0, stream>>>(pmin, bsum);
    chamfer_pass3<<<1, NT, 0, stream>>>(bsum, out);
}